// Round 1
// baseline (290.141 us; speedup 1.0000x reference)
//
#include <hip/hip_runtime.h>
#include <hip/hip_bf16.h>
#include <stdint.h>
#include <stddef.h>

#define Bb 256
#define Mm 128
#define Kc 4
#define Ee 512
#define Vv 32000
#define E3 1536

typedef __attribute__((ext_vector_type(8))) short bf16x8;
typedef __attribute__((ext_vector_type(4))) float f32x4;

__device__ __forceinline__ float bf2f(unsigned short u) {
  union { unsigned int i; float f; } v; v.i = ((unsigned int)u) << 16; return v.f;
}
__device__ __forceinline__ unsigned short f2bf(float f) {
  union { float f; unsigned int u; } v; v.f = f;
  unsigned int u = v.u;
  return (unsigned short)((u + 0x7fffu + ((u >> 16) & 1u)) >> 16);
}

// memories[t][b][m][:] = sum_k table_t[context[b,m,k]]  (bf16 out)
__global__ void gather_mem_kernel(const int* __restrict__ ctx,
                                  const float* __restrict__ A0,
                                  const float* __restrict__ A1,
                                  const float* __restrict__ A2,
                                  unsigned short* __restrict__ mem) {
  const int bm = blockIdx.x;
  const int t = blockIdx.y;
  const float* tab = (t == 0) ? A0 : (t == 1) ? A1 : A2;
  const int* c = ctx + bm * Kc;
  const int i0 = c[0], i1 = c[1], i2 = c[2], i3 = c[3];
  const int e = threadIdx.x * 4;
  float4 s0 = *(const float4*)(tab + (size_t)i0 * Ee + e);
  float4 s1 = *(const float4*)(tab + (size_t)i1 * Ee + e);
  float4 s2 = *(const float4*)(tab + (size_t)i2 * Ee + e);
  float4 s3 = *(const float4*)(tab + (size_t)i3 * Ee + e);
  float x = s0.x + s1.x + s2.x + s3.x;
  float y = s0.y + s1.y + s2.y + s3.y;
  float z = s0.z + s1.z + s2.z + s3.z;
  float w = s0.w + s1.w + s2.w + s3.w;
  ushort4 o; o.x = f2bf(x); o.y = f2bf(y); o.z = f2bf(z); o.w = f2bf(w);
  *(ushort4*)(mem + ((size_t)t * (Bb * Mm) + bm) * Ee + e) = o;
}

// m = A1[y_]  (fp32)
__global__ void gather_m_kernel(const int* __restrict__ y,
                                const float* __restrict__ A1,
                                float* __restrict__ mvec) {
  const int b = blockIdx.x;
  const int e = threadIdx.x * 4;
  const int idx = y[b];
  *(float4*)(mvec + (size_t)b * Ee + e) = *(const float4*)(A1 + (size_t)idx * Ee + e);
}

// gi = m @ W_ih^T (z=0), gh = h @ W_hh^T (z=1); fp32 tiled GEMM 64x64, BK=16
__global__ void gru_gemm_kernel(const float* __restrict__ mvec,
                                const float* __restrict__ hprev,
                                const float* __restrict__ W_ih,
                                const float* __restrict__ W_hh,
                                float* __restrict__ gi,
                                float* __restrict__ gh) {
  const int z = blockIdx.z;
  const float* A = z ? hprev : mvec;    // [256][512]
  const float* W = z ? W_hh : W_ih;     // [1536][512]
  float* C = z ? gh : gi;               // [256][1536]
  const int by = blockIdx.x * 64;
  const int jy = blockIdx.y * 64;
  __shared__ float As[16][65];
  __shared__ float Bs[16][65];
  const int tx = threadIdx.x & 15, ty = threadIdx.x >> 4;
  float acc[4][4] = {};
  for (int k0 = 0; k0 < Ee; k0 += 16) {
#pragma unroll
    for (int it = 0; it < 4; ++it) {
      int r = ty + it * 16;
      As[tx][r] = A[(size_t)(by + r) * Ee + k0 + tx];
      Bs[tx][r] = W[(size_t)(jy + r) * Ee + k0 + tx];
    }
    __syncthreads();
#pragma unroll
    for (int kk = 0; kk < 16; ++kk) {
      float a[4], bb[4];
#pragma unroll
      for (int i = 0; i < 4; ++i) { a[i] = As[kk][ty * 4 + i]; bb[i] = Bs[kk][tx * 4 + i]; }
#pragma unroll
      for (int i = 0; i < 4; ++i)
#pragma unroll
        for (int j = 0; j < 4; ++j)
          acc[i][j] += a[i] * bb[j];
    }
    __syncthreads();
  }
#pragma unroll
  for (int i = 0; i < 4; ++i)
#pragma unroll
    for (int j = 0; j < 4; ++j)
      C[(size_t)(by + ty * 4 + i) * E3 + jy + tx * 4 + j] = acc[i][j];
}

// GRU gates -> h_new; writes out_h, q, in2[:,0:512]
__global__ void gru_gate_kernel(const float* __restrict__ gi,
                                const float* __restrict__ gh,
                                const float* __restrict__ b_ih,
                                const float* __restrict__ b_hh,
                                const float* __restrict__ hprev,
                                float* __restrict__ out_h,
                                float* __restrict__ q,
                                unsigned short* __restrict__ in2) {
  const int i = blockIdx.x * blockDim.x + threadIdx.x;  // < B*E
  const int b = i >> 9, e = i & 511;
  const float* gib = gi + (size_t)b * E3;
  const float* ghb = gh + (size_t)b * E3;
  float ir = gib[e] + b_ih[e];
  float iz = gib[Ee + e] + b_ih[Ee + e];
  float inn = gib[2 * Ee + e] + b_ih[2 * Ee + e];
  float hr = ghb[e] + b_hh[e];
  float hz = ghb[Ee + e] + b_hh[Ee + e];
  float hn = ghb[2 * Ee + e] + b_hh[2 * Ee + e];
  float r = 1.f / (1.f + __expf(-(ir + hr)));
  float zz = 1.f / (1.f + __expf(-(iz + hz)));
  float n = tanhf(inn + r * hn);
  float hp = hprev[i];
  float hnew = (1.f - zz) * n + zz * hp;
  out_h[i] = hnew;
  q[i] = hnew;
  in2[(size_t)b * 1024 + e] = f2bf(hnew);
}

// One attention hop. mode: 0=hop0 (write in2 o-part + q update), 1=mid (q update),
// 2=last (write raw scores to p_out, skip softmax/o)
__global__ void hop_kernel(const unsigned short* __restrict__ memK,
                           const unsigned short* __restrict__ memV,
                           float* __restrict__ q,
                           unsigned short* __restrict__ in2,
                           float* __restrict__ p_out,
                           const int mode) {
  const int b = blockIdx.x;
  const int tid = threadIdx.x;
  const int lane = tid & 63, wid = tid >> 6;
  __shared__ float p_lds[Mm];

  // q fragment held in registers (same 8 elems reused for all 32 rows)
  const float* qb = q + (size_t)b * Ee + lane * 8;
  float qf[8];
#pragma unroll
  for (int j = 0; j < 8; ++j) qf[j] = qb[j];

  const unsigned short* kb = memK + (size_t)b * Mm * Ee + lane * 8;
#pragma unroll
  for (int ii = 0; ii < 8; ++ii) {
    uint4 ld[4];
#pragma unroll
    for (int u = 0; u < 4; ++u) {
      int m = (ii * 4 + u) * 4 + wid;
      ld[u] = *(const uint4*)(kb + (size_t)m * Ee);
    }
#pragma unroll
    for (int u = 0; u < 4; ++u) {
      const unsigned int* p4 = (const unsigned int*)&ld[u];
      float s = 0.f;
#pragma unroll
      for (int w = 0; w < 4; ++w) {
        s += bf2f((unsigned short)(p4[w] & 0xffff)) * qf[2 * w];
        s += bf2f((unsigned short)(p4[w] >> 16)) * qf[2 * w + 1];
      }
#pragma unroll
      for (int off = 32; off > 0; off >>= 1) s += __shfl_down(s, off);
      if (lane == 0) p_lds[(ii * 4 + u) * 4 + wid] = s;
    }
  }
  __syncthreads();

  if (mode == 2) {
    if (tid < Mm) p_out[b * Mm + tid] = p_lds[tid];
    return;
  }

  // softmax over 128 (wave 0 only)
  if (tid < 64) {
    float v0 = p_lds[tid], v1 = p_lds[tid + 64];
    float mx = fmaxf(v0, v1);
#pragma unroll
    for (int off = 32; off > 0; off >>= 1) mx = fmaxf(mx, __shfl_xor(mx, off));
    float e0 = __expf(v0 - mx), e1 = __expf(v1 - mx);
    float s = e0 + e1;
#pragma unroll
    for (int off = 32; off > 0; off >>= 1) s += __shfl_xor(s, off);
    float inv = 1.f / s;
    p_lds[tid] = e0 * inv;
    p_lds[tid + 64] = e1 * inv;
  }
  __syncthreads();

  // o = attn @ memV ; each thread owns 2 consecutive e
  const int e0i = tid * 2;
  const unsigned short* vb = memV + (size_t)b * Mm * Ee + e0i;
  float a0 = 0.f, a1 = 0.f;
#pragma unroll 4
  for (int m = 0; m < Mm; ++m) {
    float w = p_lds[m];
    unsigned int v = *(const unsigned int*)(vb + (size_t)m * Ee);
    a0 += w * bf2f((unsigned short)(v & 0xffff));
    a1 += w * bf2f((unsigned short)(v >> 16));
  }
  float2 qv = *(const float2*)(q + (size_t)b * Ee + e0i);
  if (mode == 0) {
    ushort2 ob; ob.x = f2bf(a0); ob.y = f2bf(a1);
    *(ushort2*)(in2 + (size_t)b * 1024 + Ee + e0i) = ob;
  }
  float2 qn; qn.x = qv.x + a0; qn.y = qv.y + a1;
  *(float2*)(q + (size_t)b * Ee + e0i) = qn;
}

// p_vocab = in2(bf16) @ lin_W^T + lin_b ; MFMA 16x16x32 bf16, tile 256x64, BK=64
__global__ __launch_bounds__(256) void pvocab_kernel(
    const unsigned short* __restrict__ in2,
    const float* __restrict__ lin_W,
    const float* __restrict__ lin_b,
    float* __restrict__ out_pv) {
  const int v0 = blockIdx.x * 64;
  const int tid = threadIdx.x;
  const int lane = tid & 63, wid = tid >> 6;
  __shared__ __align__(16) unsigned short As[Bb][72];
  __shared__ __align__(16) unsigned short Ws[64][72];

  f32x4 acc[4][4];
#pragma unroll
  for (int i = 0; i < 4; ++i)
#pragma unroll
    for (int j = 0; j < 4; ++j)
      acc[i][j] = (f32x4){0.f, 0.f, 0.f, 0.f};

  const int l15 = lane & 15, lg = lane >> 4;

  for (int k0 = 0; k0 < 1024; k0 += 64) {
    {  // stage A (bf16 direct)
      const int c = tid & 7, r0 = tid >> 3;
#pragma unroll
      for (int it = 0; it < 8; ++it) {
        int r = r0 + it * 32;
        *(uint4*)(&As[r][c * 8]) = *(const uint4*)(in2 + (size_t)r * 1024 + k0 + c * 8);
      }
    }
    {  // stage W (fp32 -> bf16)
      const int c = tid & 15, r0 = tid >> 4;
#pragma unroll
      for (int it = 0; it < 4; ++it) {
        int r = r0 + it * 16;
        float4 wv = *(const float4*)(lin_W + (size_t)(v0 + r) * 1024 + k0 + c * 4);
        ushort4 u; u.x = f2bf(wv.x); u.y = f2bf(wv.y); u.z = f2bf(wv.z); u.w = f2bf(wv.w);
        *(ushort4*)(&Ws[r][c * 4]) = u;
      }
    }
    __syncthreads();
#pragma unroll
    for (int kk = 0; kk < 2; ++kk) {
      bf16x8 af[4], wf[4];
#pragma unroll
      for (int i = 0; i < 4; ++i)
        af[i] = *(const bf16x8*)(&As[wid * 64 + i * 16 + l15][kk * 32 + lg * 8]);
#pragma unroll
      for (int i = 0; i < 4; ++i)
        wf[i] = *(const bf16x8*)(&Ws[i * 16 + l15][kk * 32 + lg * 8]);
#pragma unroll
      for (int i = 0; i < 4; ++i)
#pragma unroll
        for (int j = 0; j < 4; ++j)
          acc[i][j] = __builtin_amdgcn_mfma_f32_16x16x32_bf16(af[i], wf[j], acc[i][j], 0, 0, 0);
    }
    __syncthreads();
  }

#pragma unroll
  for (int j = 0; j < 4; ++j) {
    int v = v0 + j * 16 + l15;
    float bias = lin_b[v];
#pragma unroll
    for (int i = 0; i < 4; ++i) {
      int brow = wid * 64 + i * 16 + lg * 4;
#pragma unroll
      for (int r = 0; r < 4; ++r)
        out_pv[(size_t)(brow + r) * Vv + v] = acc[i][j][r] + bias;
    }
  }
}

extern "C" void kernel_launch(void* const* d_in, const int* in_sizes, int n_in,
                              void* d_out, int out_size, void* d_ws, size_t ws_size,
                              hipStream_t stream) {
  const int* ctx = (const int*)d_in[0];
  const int* y = (const int*)d_in[1];
  const float* h0 = (const float*)d_in[2];
  const float* A0 = (const float*)d_in[3];
  const float* A1 = (const float*)d_in[4];
  const float* A2 = (const float*)d_in[5];
  // d_in[6] (C2) is dead: memories[3] only feeds hop-2's o/q, which never reach an output
  const float* W_ih = (const float*)d_in[7];
  const float* W_hh = (const float*)d_in[8];
  const float* b_ih = (const float*)d_in[9];
  const float* b_hh = (const float*)d_in[10];
  const float* lin_W = (const float*)d_in[11];
  const float* lin_b = (const float*)d_in[12];

  char* ws = (char*)d_ws;
  const size_t MS = (size_t)Bb * Mm * Ee;          // elems per memory
  unsigned short* mem = (unsigned short*)ws;       // 3*MS bf16 = 100,663,296 B
  size_t off = 3 * MS * sizeof(unsigned short);
  float* mvec = (float*)(ws + off); off += (size_t)Bb * Ee * 4;
  float* gi = (float*)(ws + off);   off += (size_t)Bb * E3 * 4;
  float* gh = (float*)(ws + off);   off += (size_t)Bb * E3 * 4;
  float* q = (float*)(ws + off);    off += (size_t)Bb * Ee * 4;
  unsigned short* in2 = (unsigned short*)(ws + off);

  float* out = (float*)d_out;
  float* p_ptr = out;                      // [B,M]
  float* p_voc = out + Bb * Mm;            // [B,V]
  float* out_h = out + Bb * Mm + (size_t)Bb * Vv;  // [1,B,E]

  gather_mem_kernel<<<dim3(Bb * Mm, 3), 128, 0, stream>>>(ctx, A0, A1, A2, mem);
  gather_m_kernel<<<Bb, 128, 0, stream>>>(y, A1, mvec);
  gru_gemm_kernel<<<dim3(4, 24, 2), 256, 0, stream>>>(mvec, h0, W_ih, W_hh, gi, gh);
  gru_gate_kernel<<<(Bb * Ee) / 256, 256, 0, stream>>>(gi, gh, b_ih, b_hh, h0, out_h, q, in2);
  hop_kernel<<<Bb, 256, 0, stream>>>(mem, mem + MS, q, in2, nullptr, 0);
  hop_kernel<<<Bb, 256, 0, stream>>>(mem + MS, mem + 2 * MS, q, nullptr, nullptr, 1);
  hop_kernel<<<Bb, 256, 0, stream>>>(mem + 2 * MS, nullptr, q, nullptr, p_ptr, 2);
  pvocab_kernel<<<Vv / 64, 256, 0, stream>>>(in2, lin_W, lin_b, p_voc);
}

// Round 2
// 279.919 us; speedup vs baseline: 1.0365x; 1.0365x over previous
//
#include <hip/hip_runtime.h>
#include <hip/hip_bf16.h>
#include <stdint.h>
#include <stddef.h>

#define Bb 256
#define Mm 128
#define Kc 4
#define Ee 512
#define Vv 32000
#define E3 1536

typedef __attribute__((ext_vector_type(8))) short bf16x8;
typedef __attribute__((ext_vector_type(4))) float f32x4;

__device__ __forceinline__ float bf2f(unsigned short u) {
  union { unsigned int i; float f; } v; v.i = ((unsigned int)u) << 16; return v.f;
}
__device__ __forceinline__ unsigned short f2bf(float f) {
  union { float f; unsigned int u; } v; v.f = f;
  unsigned int u = v.u;
  return (unsigned short)((u + 0x7fffu + ((u >> 16) & 1u)) >> 16);
}

// fp32 table -> bf16 table (streaming)
__global__ void convert_table_kernel(const float* __restrict__ src,
                                     unsigned short* __restrict__ dst) {
  const size_t n4 = (size_t)Vv * Ee / 4;
  for (size_t i = (size_t)blockIdx.x * blockDim.x + threadIdx.x; i < n4;
       i += (size_t)gridDim.x * blockDim.x) {
    float4 v = ((const float4*)src)[i];
    ushort4 u; u.x = f2bf(v.x); u.y = f2bf(v.y); u.z = f2bf(v.z); u.w = f2bf(v.w);
    ((ushort4*)dst)[i] = u;
  }
}

// memt[bm][:] = sum_k tab_bf16[ctx[bm,k]]  ; 64 threads/block, 2 bm per block
__global__ void gather_bf16_kernel(const int* __restrict__ ctx,
                                   const unsigned short* __restrict__ tab,
                                   unsigned short* __restrict__ memt) {
  const int bm0 = blockIdx.x;  // 0..16383
  const int e = threadIdx.x * 8;
  const int4 ca = *(const int4*)(ctx + bm0 * 4);
  const int4 cb = *(const int4*)(ctx + (bm0 + 16384) * 4);
  uint4 r[8];
  r[0] = *(const uint4*)(tab + (size_t)ca.x * Ee + e);
  r[1] = *(const uint4*)(tab + (size_t)ca.y * Ee + e);
  r[2] = *(const uint4*)(tab + (size_t)ca.z * Ee + e);
  r[3] = *(const uint4*)(tab + (size_t)ca.w * Ee + e);
  r[4] = *(const uint4*)(tab + (size_t)cb.x * Ee + e);
  r[5] = *(const uint4*)(tab + (size_t)cb.y * Ee + e);
  r[6] = *(const uint4*)(tab + (size_t)cb.z * Ee + e);
  r[7] = *(const uint4*)(tab + (size_t)cb.w * Ee + e);
#pragma unroll
  for (int h = 0; h < 2; ++h) {
    float s[8];
#pragma unroll
    for (int w = 0; w < 4; ++w) {
      const unsigned int* p0 = (const unsigned int*)&r[h * 4 + 0];
      const unsigned int* p1 = (const unsigned int*)&r[h * 4 + 1];
      const unsigned int* p2 = (const unsigned int*)&r[h * 4 + 2];
      const unsigned int* p3 = (const unsigned int*)&r[h * 4 + 3];
      s[2 * w] = bf2f((unsigned short)(p0[w] & 0xffff)) + bf2f((unsigned short)(p1[w] & 0xffff)) +
                 bf2f((unsigned short)(p2[w] & 0xffff)) + bf2f((unsigned short)(p3[w] & 0xffff));
      s[2 * w + 1] = bf2f((unsigned short)(p0[w] >> 16)) + bf2f((unsigned short)(p1[w] >> 16)) +
                     bf2f((unsigned short)(p2[w] >> 16)) + bf2f((unsigned short)(p3[w] >> 16));
    }
    unsigned int o[4];
#pragma unroll
    for (int w = 0; w < 4; ++w)
      o[w] = (unsigned int)f2bf(s[2 * w]) | ((unsigned int)f2bf(s[2 * w + 1]) << 16);
    const int bm = bm0 + h * 16384;
    *(uint4*)(memt + (size_t)bm * Ee + e) = *(uint4*)o;
  }
}

// fallback: memories[t][bm][:] = sum_k table_t[ctx] from fp32 tables (round-1 path)
__global__ void gather_mem_f32_kernel(const int* __restrict__ ctx,
                                      const float* __restrict__ A0,
                                      const float* __restrict__ A1,
                                      const float* __restrict__ A2,
                                      unsigned short* __restrict__ mem) {
  const int bm = blockIdx.x;
  const int t = blockIdx.y;
  const float* tab = (t == 0) ? A0 : (t == 1) ? A1 : A2;
  const int* c = ctx + bm * Kc;
  const int i0 = c[0], i1 = c[1], i2 = c[2], i3 = c[3];
  const int e = threadIdx.x * 4;
  float4 s0 = *(const float4*)(tab + (size_t)i0 * Ee + e);
  float4 s1 = *(const float4*)(tab + (size_t)i1 * Ee + e);
  float4 s2 = *(const float4*)(tab + (size_t)i2 * Ee + e);
  float4 s3 = *(const float4*)(tab + (size_t)i3 * Ee + e);
  float x = s0.x + s1.x + s2.x + s3.x;
  float y = s0.y + s1.y + s2.y + s3.y;
  float z = s0.z + s1.z + s2.z + s3.z;
  float w = s0.w + s1.w + s2.w + s3.w;
  ushort4 o; o.x = f2bf(x); o.y = f2bf(y); o.z = f2bf(z); o.w = f2bf(w);
  *(ushort4*)(mem + ((size_t)t * (Bb * Mm) + bm) * Ee + e) = o;
}

// m = A1[y_]  (fp32)
__global__ void gather_m_kernel(const int* __restrict__ y,
                                const float* __restrict__ A1,
                                float* __restrict__ mvec) {
  const int b = blockIdx.x;
  const int e = threadIdx.x * 4;
  const int idx = y[b];
  *(float4*)(mvec + (size_t)b * Ee + e) = *(const float4*)(A1 + (size_t)idx * Ee + e);
}

// gi = m @ W_ih^T (z=0), gh = h @ W_hh^T (z=1); fp32 tiled GEMM 64x64, BK=16
__global__ void gru_gemm_kernel(const float* __restrict__ mvec,
                                const float* __restrict__ hprev,
                                const float* __restrict__ W_ih,
                                const float* __restrict__ W_hh,
                                float* __restrict__ gi,
                                float* __restrict__ gh) {
  const int z = blockIdx.z;
  const float* A = z ? hprev : mvec;    // [256][512]
  const float* W = z ? W_hh : W_ih;     // [1536][512]
  float* C = z ? gh : gi;               // [256][1536]
  const int by = blockIdx.x * 64;
  const int jy = blockIdx.y * 64;
  __shared__ float As[16][65];
  __shared__ float Bs[16][65];
  const int tx = threadIdx.x & 15, ty = threadIdx.x >> 4;
  float acc[4][4] = {};
  for (int k0 = 0; k0 < Ee; k0 += 16) {
#pragma unroll
    for (int it = 0; it < 4; ++it) {
      int r = ty + it * 16;
      As[tx][r] = A[(size_t)(by + r) * Ee + k0 + tx];
      Bs[tx][r] = W[(size_t)(jy + r) * Ee + k0 + tx];
    }
    __syncthreads();
#pragma unroll
    for (int kk = 0; kk < 16; ++kk) {
      float a[4], bb[4];
#pragma unroll
      for (int i = 0; i < 4; ++i) { a[i] = As[kk][ty * 4 + i]; bb[i] = Bs[kk][tx * 4 + i]; }
#pragma unroll
      for (int i = 0; i < 4; ++i)
#pragma unroll
        for (int j = 0; j < 4; ++j)
          acc[i][j] += a[i] * bb[j];
    }
    __syncthreads();
  }
#pragma unroll
  for (int i = 0; i < 4; ++i)
#pragma unroll
    for (int j = 0; j < 4; ++j)
      C[(size_t)(by + ty * 4 + i) * E3 + jy + tx * 4 + j] = acc[i][j];
}

// GRU gates -> h_new; writes out_h, q, in2[:,0:512]
__global__ void gru_gate_kernel(const float* __restrict__ gi,
                                const float* __restrict__ gh,
                                const float* __restrict__ b_ih,
                                const float* __restrict__ b_hh,
                                const float* __restrict__ hprev,
                                float* __restrict__ out_h,
                                float* __restrict__ q,
                                unsigned short* __restrict__ in2) {
  const int i = blockIdx.x * blockDim.x + threadIdx.x;  // < B*E
  const int b = i >> 9, e = i & 511;
  const float* gib = gi + (size_t)b * E3;
  const float* ghb = gh + (size_t)b * E3;
  float ir = gib[e] + b_ih[e];
  float iz = gib[Ee + e] + b_ih[Ee + e];
  float inn = gib[2 * Ee + e] + b_ih[2 * Ee + e];
  float hr = ghb[e] + b_hh[e];
  float hz = ghb[Ee + e] + b_hh[Ee + e];
  float hn = ghb[2 * Ee + e] + b_hh[2 * Ee + e];
  float r = 1.f / (1.f + __expf(-(ir + hr)));
  float zz = 1.f / (1.f + __expf(-(iz + hz)));
  float n = tanhf(inn + r * hn);
  float hp = hprev[i];
  float hnew = (1.f - zz) * n + zz * hp;
  out_h[i] = hnew;
  q[i] = hnew;
  in2[(size_t)b * 1024 + e] = f2bf(hnew);
}

// One attention hop. mode: 0=hop0 (write in2 o-part + q update), 1=mid (q update),
// 2=last (write raw scores to p_out, skip softmax/o)
__global__ void hop_kernel(const unsigned short* __restrict__ memK,
                           const unsigned short* __restrict__ memV,
                           float* __restrict__ q,
                           unsigned short* __restrict__ in2,
                           float* __restrict__ p_out,
                           const int mode) {
  const int b = blockIdx.x;
  const int tid = threadIdx.x;
  const int lane = tid & 63, wid = tid >> 6;
  __shared__ float p_lds[Mm];

  const float* qb = q + (size_t)b * Ee + lane * 8;
  float qf[8];
#pragma unroll
  for (int j = 0; j < 8; ++j) qf[j] = qb[j];

  const unsigned short* kb = memK + (size_t)b * Mm * Ee + lane * 8;
#pragma unroll
  for (int ii = 0; ii < 8; ++ii) {
    uint4 ld[4];
#pragma unroll
    for (int u = 0; u < 4; ++u) {
      int m = (ii * 4 + u) * 4 + wid;
      ld[u] = *(const uint4*)(kb + (size_t)m * Ee);
    }
#pragma unroll
    for (int u = 0; u < 4; ++u) {
      const unsigned int* p4 = (const unsigned int*)&ld[u];
      float s = 0.f;
#pragma unroll
      for (int w = 0; w < 4; ++w) {
        s += bf2f((unsigned short)(p4[w] & 0xffff)) * qf[2 * w];
        s += bf2f((unsigned short)(p4[w] >> 16)) * qf[2 * w + 1];
      }
#pragma unroll
      for (int off = 32; off > 0; off >>= 1) s += __shfl_down(s, off);
      if (lane == 0) p_lds[(ii * 4 + u) * 4 + wid] = s;
    }
  }
  __syncthreads();

  if (mode == 2) {
    if (tid < Mm) p_out[b * Mm + tid] = p_lds[tid];
    return;
  }

  if (tid < 64) {
    float v0 = p_lds[tid], v1 = p_lds[tid + 64];
    float mx = fmaxf(v0, v1);
#pragma unroll
    for (int off = 32; off > 0; off >>= 1) mx = fmaxf(mx, __shfl_xor(mx, off));
    float e0 = __expf(v0 - mx), e1 = __expf(v1 - mx);
    float s = e0 + e1;
#pragma unroll
    for (int off = 32; off > 0; off >>= 1) s += __shfl_xor(s, off);
    float inv = 1.f / s;
    p_lds[tid] = e0 * inv;
    p_lds[tid + 64] = e1 * inv;
  }
  __syncthreads();

  const int e0i = tid * 2;
  const unsigned short* vb = memV + (size_t)b * Mm * Ee + e0i;
  float a0 = 0.f, a1 = 0.f;
#pragma unroll 4
  for (int m = 0; m < Mm; ++m) {
    float w = p_lds[m];
    unsigned int v = *(const unsigned int*)(vb + (size_t)m * Ee);
    a0 += w * bf2f((unsigned short)(v & 0xffff));
    a1 += w * bf2f((unsigned short)(v >> 16));
  }
  float2 qv = *(const float2*)(q + (size_t)b * Ee + e0i);
  if (mode == 0) {
    ushort2 ob; ob.x = f2bf(a0); ob.y = f2bf(a1);
    *(ushort2*)(in2 + (size_t)b * 1024 + Ee + e0i) = ob;
  }
  float2 qn; qn.x = qv.x + a0; qn.y = qv.y + a1;
  *(float2*)(q + (size_t)b * Ee + e0i) = qn;
}

// p_vocab = in2(bf16) @ lin_W^T + lin_b ; MFMA 16x16x32 bf16, tile 256x64, BK=64
__global__ __launch_bounds__(256) void pvocab_kernel(
    const unsigned short* __restrict__ in2,
    const float* __restrict__ lin_W,
    const float* __restrict__ lin_b,
    float* __restrict__ out_pv) {
  const int v0 = blockIdx.x * 64;
  const int tid = threadIdx.x;
  const int lane = tid & 63, wid = tid >> 6;
  __shared__ __align__(16) unsigned short As[Bb][72];
  __shared__ __align__(16) unsigned short Ws[64][72];

  f32x4 acc[4][4];
#pragma unroll
  for (int i = 0; i < 4; ++i)
#pragma unroll
    for (int j = 0; j < 4; ++j)
      acc[i][j] = (f32x4){0.f, 0.f, 0.f, 0.f};

  const int l15 = lane & 15, lg = lane >> 4;

  for (int k0 = 0; k0 < 1024; k0 += 64) {
    {
      const int c = tid & 7, r0 = tid >> 3;
#pragma unroll
      for (int it = 0; it < 8; ++it) {
        int r = r0 + it * 32;
        *(uint4*)(&As[r][c * 8]) = *(const uint4*)(in2 + (size_t)r * 1024 + k0 + c * 8);
      }
    }
    {
      const int c = tid & 15, r0 = tid >> 4;
#pragma unroll
      for (int it = 0; it < 4; ++it) {
        int r = r0 + it * 16;
        float4 wv = *(const float4*)(lin_W + (size_t)(v0 + r) * 1024 + k0 + c * 4);
        ushort4 u; u.x = f2bf(wv.x); u.y = f2bf(wv.y); u.z = f2bf(wv.z); u.w = f2bf(wv.w);
        *(ushort4*)(&Ws[r][c * 4]) = u;
      }
    }
    __syncthreads();
#pragma unroll
    for (int kk = 0; kk < 2; ++kk) {
      bf16x8 af[4], wf[4];
#pragma unroll
      for (int i = 0; i < 4; ++i)
        af[i] = *(const bf16x8*)(&As[wid * 64 + i * 16 + l15][kk * 32 + lg * 8]);
#pragma unroll
      for (int i = 0; i < 4; ++i)
        wf[i] = *(const bf16x8*)(&Ws[i * 16 + l15][kk * 32 + lg * 8]);
#pragma unroll
      for (int i = 0; i < 4; ++i)
#pragma unroll
        for (int j = 0; j < 4; ++j)
          acc[i][j] = __builtin_amdgcn_mfma_f32_16x16x32_bf16(af[i], wf[j], acc[i][j], 0, 0, 0);
    }
    __syncthreads();
  }

#pragma unroll
  for (int j = 0; j < 4; ++j) {
    int v = v0 + j * 16 + l15;
    float bias = lin_b[v];
#pragma unroll
    for (int i = 0; i < 4; ++i) {
      int brow = wid * 64 + i * 16 + lg * 4;
#pragma unroll
      for (int r = 0; r < 4; ++r)
        out_pv[(size_t)(brow + r) * Vv + v] = acc[i][j][r] + bias;
    }
  }
}

extern "C" void kernel_launch(void* const* d_in, const int* in_sizes, int n_in,
                              void* d_out, int out_size, void* d_ws, size_t ws_size,
                              hipStream_t stream) {
  const int* ctx = (const int*)d_in[0];
  const int* y = (const int*)d_in[1];
  const float* h0 = (const float*)d_in[2];
  const float* A0 = (const float*)d_in[3];
  const float* A1 = (const float*)d_in[4];
  const float* A2 = (const float*)d_in[5];
  // d_in[6] (C2) dead: memories[3] only feeds hop-2's o/q, which never reach an output
  const float* W_ih = (const float*)d_in[7];
  const float* W_hh = (const float*)d_in[8];
  const float* b_ih = (const float*)d_in[9];
  const float* b_hh = (const float*)d_in[10];
  const float* lin_W = (const float*)d_in[11];
  const float* lin_b = (const float*)d_in[12];

  const size_t MS = (size_t)Bb * Mm * Ee;               // elems per memory
  const size_t TB = (size_t)Vv * Ee;                    // elems per table
  const size_t bufBytes = TB * sizeof(unsigned short);  // 32,768,000
  const size_t memBytes = 3 * MS * sizeof(unsigned short);
  const size_t smallBytes = ((size_t)Bb * Ee + 2 * (size_t)Bb * E3 + (size_t)Bb * Ee) * 4 +
                            (size_t)Bb * 1024 * 2;
  const bool bf16path = ws_size >= bufBytes + memBytes + smallBytes;

  char* ws = (char*)d_ws;
  unsigned short* tabbuf = nullptr;
  unsigned short* mem;
  size_t off = 0;
  if (bf16path) {
    tabbuf = (unsigned short*)ws; off += bufBytes;
  }
  mem = (unsigned short*)(ws + off); off += memBytes;
  float* mvec = (float*)(ws + off); off += (size_t)Bb * Ee * 4;
  float* gi = (float*)(ws + off);   off += (size_t)Bb * E3 * 4;
  float* gh = (float*)(ws + off);   off += (size_t)Bb * E3 * 4;
  float* q = (float*)(ws + off);    off += (size_t)Bb * Ee * 4;
  unsigned short* in2 = (unsigned short*)(ws + off);

  float* out = (float*)d_out;
  float* p_ptr = out;                              // [B,M]
  float* p_voc = out + Bb * Mm;                    // [B,V]
  float* out_h = out + Bb * Mm + (size_t)Bb * Vv;  // [1,B,E]

  if (bf16path) {
    const float* tabs[3] = {A0, A1, A2};
    for (int t = 0; t < 3; ++t) {
      convert_table_kernel<<<2048, 256, 0, stream>>>(tabs[t], tabbuf);
      gather_bf16_kernel<<<Bb * Mm / 2, 64, 0, stream>>>(ctx, tabbuf, mem + t * MS);
    }
  } else {
    gather_mem_f32_kernel<<<dim3(Bb * Mm, 3), 128, 0, stream>>>(ctx, A0, A1, A2, mem);
  }
  gather_m_kernel<<<Bb, 128, 0, stream>>>(y, A1, mvec);
  gru_gemm_kernel<<<dim3(4, 24, 2), 256, 0, stream>>>(mvec, h0, W_ih, W_hh, gi, gh);
  gru_gate_kernel<<<(Bb * Ee) / 256, 256, 0, stream>>>(gi, gh, b_ih, b_hh, h0, out_h, q, in2);
  hop_kernel<<<Bb, 256, 0, stream>>>(mem, mem + MS, q, in2, nullptr, 0);
  hop_kernel<<<Bb, 256, 0, stream>>>(mem + MS, mem + 2 * MS, q, nullptr, nullptr, 1);
  hop_kernel<<<Bb, 256, 0, stream>>>(mem + 2 * MS, nullptr, q, nullptr, p_ptr, 2);
  pvocab_kernel<<<Vv / 64, 256, 0, stream>>>(in2, lin_W, lin_b, p_voc);
}